// Round 2
// baseline (2731.339 us; speedup 1.0000x reference)
//
#include <hip/hip_runtime.h>
#include <hip/hip_bf16.h>

// TimeLSTM: B=2048, T=256, IN=65 (1 time-delta + 64 features), H=256, gates=1024.
//
// Round 2: latency attack. 128 persistent blocks x 512 threads (8 waves, 2/SIMD).
//  - Each wave owns an N-slice of 8 fragments (128 gate-cols) per k-step.
//  - W_ih (k-tiles 0,1 = 128KB bf16) LDS-resident; W_hh (k-tiles 2..9) streamed
//    from L2 with an explicit register double-buffer (8 loads in flight while
//    MFMA-ing the previous k-tile).
//  - x(t+1) prefetched into registers during the GEMM phase of step t.
//  - Lane-local gate fusion: wave w covers cols wq*64 + (wh*2+jt)*16 + l15,
//    wq=w>>1, wh=w&1, jt=0..1; all four gates (g=0..3) for those cols live in
//    the same lane -> epilogue has no cross-lane traffic.
//  - C/D layout (m89): col = lane&15, row = (lane>>4)*4 + reg.

typedef __bf16 v8bf __attribute__((ext_vector_type(8)));
typedef __bf16 v2bf __attribute__((ext_vector_type(2)));
typedef float f32x4 __attribute__((ext_vector_type(4)));

#define B_SZ 2048
#define T_SZ 256
#define IN_SZ 65
#define H_SZ 256
#define NKT 10          // 320 / 32 k-steps
#define RES_KT 2        // k-tiles resident in LDS (= W_ih exactly)
#define MBLK 16
#define NBLOCKS (B_SZ / MBLK)   // 128
#define THREADS 512

#define WRES_BYTES (RES_KT * 64 * 1024)       // 131072
#define A_STRIDE 328                           // 320 + 8 bf16 pad
#define A_BYTES (16 * A_STRIDE * 2)            // 10496
#define SMEM_TOTAL (WRES_BYTES + A_BYTES + 64 + 64)

__device__ __forceinline__ float fsig(float xv) {
    return __builtin_amdgcn_rcpf(1.f + __expf(-xv));
}
__device__ __forceinline__ float ftanh(float xv) {
    return fmaf(2.f, fsig(2.f * xv), -1.f);
}

// ---------------- prep: swizzle W into MFMA B-fragment order (bf16) ----------------
// 640 fragments (kt 0..9, wq 0..3, nt 0..15), 1KB each: total 640KB in d_ws.
// frag(kt,wq,nt): lane L holds W[n][k], n = (nt>>2)*256 + wq*64 + (nt&3)*16 + (L&15),
//                 k = kt*32 + (L>>4)*8 + j, j=0..7.
__global__ void prep_w(const float* __restrict__ W_ih, const float* __restrict__ W_hh,
                       __bf16* __restrict__ wsz) {
    int gtid = blockIdx.x * 256 + threadIdx.x;   // 0..40959
    int lane = gtid & 63;
    int frag = gtid >> 6;                        // 0..639
    int kt = frag >> 6;
    int wq = (frag >> 4) & 3;
    int nt = frag & 15;
    int g = nt >> 2, jt = nt & 3;
    int n  = g * 256 + wq * 64 + jt * 16 + (lane & 15);
    int k0 = kt * 32 + ((lane >> 4) << 3);
    v8bf v;
#pragma unroll
    for (int j = 0; j < 8; ++j) {
        int k = k0 + j;
        float f = (k < 64) ? W_ih[n * 64 + k] : W_hh[n * 256 + (k - 64)];
        v[j] = (__bf16)f;
    }
    *reinterpret_cast<v8bf*>(wsz + (size_t)frag * 512 + lane * 8) = v;
}

// ---------------- fused persistent scan ----------------
__global__ __launch_bounds__(THREADS, 2) void tlstm_scan(
    const float* __restrict__ x, const __bf16* __restrict__ wsz,
    const float* __restrict__ b_ih, const float* __restrict__ b_hh,
    const float* __restrict__ Wt, const float* __restrict__ bt,
    const float* __restrict__ Wf, const float* __restrict__ bfp,
    float* __restrict__ out) {
    extern __shared__ char smem[];
    __bf16* Wres  = reinterpret_cast<__bf16*>(smem);                       // 128KB
    __bf16* A     = reinterpret_cast<__bf16*>(smem + WRES_BYTES);          // 16 x 328 bf16
    float* td_lds = reinterpret_cast<float*>(smem + WRES_BYTES + A_BYTES); // 16 f32
    float* out_acc = reinterpret_cast<float*>(smem + WRES_BYTES + A_BYTES + 64);

    const int tid  = threadIdx.x;
    const int lane = tid & 63;
    const int w    = tid >> 6;     // 0..7
    const int wq   = w >> 1;       // 0..3  N-quadrant
    const int wh   = w & 1;        // 0..1  jt-pair within quadrant
    const int l15  = lane & 15;
    const int lhi  = lane >> 4;
    const int b0   = blockIdx.x * MBLK;

    // one-time: copy resident W k-tiles (frag 0..127, 128KB) into LDS
    {
        const uint4* src = reinterpret_cast<const uint4*>(wsz);
        uint4* dst = reinterpret_cast<uint4*>(Wres);
#pragma unroll
        for (int i = 0; i < 16; ++i) dst[tid + i * THREADS] = src[tid + i * THREADS];
    }
    // zero A (h region must start at 0)
    for (int i = tid; i < 16 * A_STRIDE; i += THREADS) A[i] = (__bf16)0.f;
    if (tid < 16) out_acc[tid] = 0.f;

    // per-lane constants: 2 column slots jt=0..1 at col = wq*64 + (wh*2+jt)*16 + l15
    float bias[4][2], wt_r[2], bt_r[2], wf_r[2];
#pragma unroll
    for (int jt = 0; jt < 2; ++jt) {
        int col = wq * 64 + (wh * 2 + jt) * 16 + l15;
#pragma unroll
        for (int g = 0; g < 4; ++g) bias[g][jt] = b_ih[g * 256 + col] + b_hh[g * 256 + col];
        wt_r[jt] = Wt[col];
        bt_r[jt] = bt[col];
        wf_r[jt] = Wf[col];
    }

    float cst[2][4];   // fp32 cell state: [jt][reg]
#pragma unroll
    for (int jt = 0; jt < 2; ++jt)
#pragma unroll
        for (int r = 0; r < 4; ++r) cst[jt][r] = 0.f;
    float outp[4] = {0.f, 0.f, 0.f, 0.f};

    // x staging: 512 threads cover 16 rows x 32 chunks of 2 features
    const int xr = tid >> 5;   // row 0..15
    const int xc = tid & 31;   // feature pair 0..31
    const float* xbase = x + (size_t)(b0 + xr) * T_SZ * IN_SZ;

    // prefetch x(t=0)
    float px0, px1, ptd = 0.f;
    {
        const float* p = xbase;
        px0 = p[1 + xc * 2];
        px1 = p[2 + xc * 2];
        if (xc == 0) ptd = p[0];
    }

    // fragment base offset for this wave's slice: frag(kt, wq, g*4 + wh*2 + jt)
    // flat frag id = (kt*4 + wq)*16 + g*4 + wh*2 + jt
    const __bf16* wsz_l = wsz + (size_t)lane * 8;          // lane part folded in
    const __bf16* wres_l = Wres + (size_t)lane * 8;

    __syncthreads();           // Wres copy + A zero visible

    for (int t = 0; t < T_SZ; ++t) {
        // ---- stage x_t (from prefetch regs) + td into LDS
        {
            v2bf vv;
            vv[0] = (__bf16)px0; vv[1] = (__bf16)px1;
            *reinterpret_cast<v2bf*>(A + xr * A_STRIDE + xc * 2) = vv;
            if (xc == 0) td_lds[xr] = ptd;
        }
        __syncthreads();   // barrier A: x_t + h(t-1) ready in LDS

        // ---- issue x(t+1) prefetch (consumed at next staging; overlaps GEMM)
        {
            int tn = (t + 1 < T_SZ) ? t + 1 : t;
            const float* p = xbase + (size_t)tn * IN_SZ;
            px0 = p[1 + xc * 2];
            px1 = p[2 + xc * 2];
            if (xc == 0) ptd = p[0];
        }

        // ---- A fragments: lane holds A[m=l15][k = kt*32 + lhi*8 + 0..7]
        v8bf a[NKT];
#pragma unroll
        for (int kt = 0; kt < NKT; ++kt)
            a[kt] = *reinterpret_cast<const v8bf*>(A + l15 * A_STRIDE + kt * 32 + lhi * 8);

        float tdv[4];
#pragma unroll
        for (int r = 0; r < 4; ++r) tdv[r] = td_lds[lhi * 4 + r];

        f32x4 acc[8];
#pragma unroll
        for (int i = 0; i < 8; ++i) acc[i] = (f32x4){0.f, 0.f, 0.f, 0.f};

        // ---- register double-buffer prefetch of first streamed k-tile (kt=2)
        v8bf bn[8];
#pragma unroll
        for (int i = 0; i < 8; ++i) {
            int frag = (2 * 4 + wq) * 16 + (i >> 1) * 4 + wh * 2 + (i & 1);
            bn[i] = *reinterpret_cast<const v8bf*>(wsz_l + (size_t)frag * 512);
        }

        // ---- k-tiles 0,1 from LDS-resident W_ih
#pragma unroll
        for (int kt = 0; kt < RES_KT; ++kt) {
#pragma unroll
            for (int i = 0; i < 8; ++i) {
                int frag = (kt * 4 + wq) * 16 + (i >> 1) * 4 + wh * 2 + (i & 1);
                v8bf b = *reinterpret_cast<const v8bf*>(wres_l + (size_t)frag * 512);
                acc[i] = __builtin_amdgcn_mfma_f32_16x16x32_bf16(a[kt], b, acc[i], 0, 0, 0);
            }
        }

        // ---- streamed k-tiles 2..9: MFMA current regs while loading next
#pragma unroll
        for (int kt = RES_KT; kt < NKT; ++kt) {
            v8bf bc[8];
#pragma unroll
            for (int i = 0; i < 8; ++i) bc[i] = bn[i];
            if (kt < NKT - 1) {
#pragma unroll
                for (int i = 0; i < 8; ++i) {
                    int frag = ((kt + 1) * 4 + wq) * 16 + (i >> 1) * 4 + wh * 2 + (i & 1);
                    bn[i] = *reinterpret_cast<const v8bf*>(wsz_l + (size_t)frag * 512);
                }
            }
#pragma unroll
            for (int i = 0; i < 8; ++i)
                acc[i] = __builtin_amdgcn_mfma_f32_16x16x32_bf16(a[kt], bc[i], acc[i], 0, 0, 0);
        }
        __syncthreads();   // barrier B: all A reads done before h is overwritten

        // ---- lane-local LSTM epilogue (all 4 gates for this lane's 2 columns)
        const bool last = (t == T_SZ - 1);
#pragma unroll
        for (int jt = 0; jt < 2; ++jt) {
#pragma unroll
            for (int r = 0; r < 4; ++r) {
                float pi = acc[0 * 2 + jt][r] + bias[0][jt];
                float pf = acc[1 * 2 + jt][r] + bias[1][jt];
                float pg = acc[2 * 2 + jt][r] + bias[2][jt];
                float po = acc[3 * 2 + jt][r] + bias[3][jt];
                float d  = fsig(fmaf(tdv[r], wt_r[jt], bt_r[jt]));
                float c  = cst[jt][r] * d;                    // c *= decay
                c = fsig(pf) * c + fsig(pi) * ftanh(pg);      // c = f*c + i*g
                cst[jt][r] = c;
                float h = fsig(po) * ftanh(c);                // h = o*tanh(c)
                int row = lhi * 4 + r;
                int col = wq * 64 + (wh * 2 + jt) * 16 + l15;
                A[row * A_STRIDE + 64 + col] = (__bf16)h;     // h -> A layout for next step
                if (last) outp[r] = fmaf(h, wf_r[jt], outp[r]);
            }
        }
    }

    // ---- output: out[b] = h_T . Wf + bf
#pragma unroll
    for (int r = 0; r < 4; ++r) atomicAdd(&out_acc[lhi * 4 + r], outp[r]);
    __syncthreads();
    if (tid < 16) out[b0 + tid] = out_acc[tid] + bfp[0];
}

extern "C" void kernel_launch(void* const* d_in, const int* in_sizes, int n_in,
                              void* d_out, int out_size, void* d_ws, size_t ws_size,
                              hipStream_t stream) {
    const float* x    = (const float*)d_in[0];
    const float* W_ih = (const float*)d_in[1];
    const float* W_hh = (const float*)d_in[2];
    const float* b_ih = (const float*)d_in[3];
    const float* b_hh = (const float*)d_in[4];
    const float* Wt   = (const float*)d_in[5];
    const float* bt   = (const float*)d_in[6];
    const float* Wf   = (const float*)d_in[7];
    const float* bfp  = (const float*)d_in[8];
    float* out  = (float*)d_out;
    __bf16* wsz = (__bf16*)d_ws;   // 640KB of swizzled bf16 W

    (void)in_sizes; (void)n_in; (void)out_size; (void)ws_size;

    hipFuncSetAttribute(reinterpret_cast<const void*>(tlstm_scan),
                        hipFuncAttributeMaxDynamicSharedMemorySize, SMEM_TOTAL);

    prep_w<<<dim3(160), dim3(256), 0, stream>>>(W_ih, W_hh, wsz);
    tlstm_scan<<<dim3(NBLOCKS), dim3(THREADS), SMEM_TOTAL, stream>>>(
        x, wsz, b_ih, b_hh, Wt, bt, Wf, bfp, out);
}